// Round 8
// baseline (246.375 us; speedup 1.0000x reference)
//
#include <hip/hip_runtime.h>

// QWTForward: all 16 output blocks are (S_A*S_B) * D, D = bicubic downsample.
// R6 post-mortem: dur_us = harness poison-fill (~122us, 805MB @6.6TB/s) + kernel.
// Kernel was ~120us = 2.1 TB/s on 252MB -- 3x off what the fill proves possible.
// R7 theory: 16-way interleaved per-wave write streams (2KB per stream before
// jumping) defeat HBM write locality. Restructure: block computes a 16x256
// D-slab of one plane into LDS, then each wave owns output tensor t=wave and
// writes its 4 channel-block streams as 16KB sequential bursts.

#define BW0 -0.09375f
#define BW1  0.59375f
#define BW2  0.59375f
#define BW3 -0.09375f

#define H_IN  512
#define W_IN  512
#define H_OUT 256
#define W_OUT 256
#define PLANE_OUT (H_OUT * W_OUT)          // 65536
#define TENSOR_STRIDE (16 * 12 * PLANE_OUT) // floats per out tensor

typedef __attribute__((ext_vector_type(4))) float f32x4;

__global__ __launch_bounds__(256) void qwt_fused_kernel(
    const float* __restrict__ img,
    const float* __restrict__ gl, const float* __restrict__ gh,
    const float* __restrict__ fl, const float* __restrict__ fh,
    float* __restrict__ out)
{
    __shared__ float s_scale[16];
    __shared__ __align__(16) float sD[16][W_OUT];   // 16 KB D-slab

    const int tid = threadIdx.x;

    // ---- wave 0: filter sums + 16 scale products -> LDS ----
    if (tid < 64) {
        float vgl = 0.f, vgh = 0.f, vfl = 0.f, vfh = 0.f;
        if (tid < 30) { vgl = gl[tid]; vgh = gh[tid]; vfl = fl[tid]; vfh = fh[tid]; }
        #pragma unroll
        for (int m = 32; m >= 1; m >>= 1) {
            vgl += __shfl_xor(vgl, m);
            vgh += __shfl_xor(vgh, m);
            vfl += __shfl_xor(vfl, m);
            vfh += __shfl_xor(vfh, m);
        }
        if (tid < 16) {
            const int t = tid >> 2, cb = tid & 3;
            const float A = (t < 2) ? ((cb & 1) ? vfl : vgl)
                                    : ((cb & 1) ? vfh : vgh);
            const float B = (t & 1) ? ((cb < 2) ? vgh : vfh)
                                    : ((cb < 2) ? vgl : vfl);
            s_scale[tid] = A * B;
        }
    }

    // ---- phase A: compute D slab (16 out rows x 256 cols) into LDS ----
    // block -> (bc, slab): 48 planes x 16 slabs = 768 blocks
    const int blk = blockIdx.x;
    const int s   = blk & 15;            // slab: out rows 16s .. 16s+15
    const int bc  = blk >> 4;            // b*3 + c, 0..47

    const float* plane = img + (size_t)bc * (H_IN * W_IN);

    const int w4  = tid & 63;            // out col group: cols 4w4..4w4+3
    const int hpL = tid >> 6;            // 0..3; units hp = hpL, hpL+4

    const int cbase = w4 * 8;            // input cols 8w4..8w4+7 in-bounds
    int clo = cbase - 1; if (clo < 0) clo = 0;
    int chi = cbase + 8; if (chi > W_IN - 1) chi = W_IN - 1;

    #pragma unroll
    for (int u = 0; u < 2; ++u) {
        const int hp = hpL + 4 * u;      // row-pair within slab, 0..7

        // 6 clamped source rows: 32s+4hp-1 .. 32s+4hp+4
        int r[6];
        #pragma unroll
        for (int i = 0; i < 6; ++i) {
            int rr = 32 * s + 4 * hp - 1 + i;
            r[i] = rr < 0 ? 0 : (rr > H_IN - 1 ? H_IN - 1 : rr);
        }

        float hv[6][4];
        #pragma unroll
        for (int i = 0; i < 6; ++i) {
            const float* rowp = plane + (size_t)r[i] * W_IN;
            const float4 a  = *(const float4*)(rowp + cbase);
            const float4 b4 = *(const float4*)(rowp + cbase + 4);
            const float v0 = rowp[clo];
            const float v9 = rowp[chi];
            const float v1 = a.x,  v2 = a.y,  v3 = a.z,  v4 = a.w;
            const float v5 = b4.x, v6 = b4.y, v7 = b4.z, v8 = b4.w;
            hv[i][0] = BW0 * v0 + BW1 * v1 + BW2 * v2 + BW3 * v3;
            hv[i][1] = BW0 * v2 + BW1 * v3 + BW2 * v4 + BW3 * v5;
            hv[i][2] = BW0 * v4 + BW1 * v5 + BW2 * v6 + BW3 * v7;
            hv[i][3] = BW0 * v6 + BW1 * v7 + BW2 * v8 + BW3 * v9;
        }

        f32x4 d0, d1;
        d0.x = BW0 * hv[0][0] + BW1 * hv[1][0] + BW2 * hv[2][0] + BW3 * hv[3][0];
        d0.y = BW0 * hv[0][1] + BW1 * hv[1][1] + BW2 * hv[2][1] + BW3 * hv[3][1];
        d0.z = BW0 * hv[0][2] + BW1 * hv[1][2] + BW2 * hv[2][2] + BW3 * hv[3][2];
        d0.w = BW0 * hv[0][3] + BW1 * hv[1][3] + BW2 * hv[2][3] + BW3 * hv[3][3];
        d1.x = BW0 * hv[2][0] + BW1 * hv[3][0] + BW2 * hv[4][0] + BW3 * hv[5][0];
        d1.y = BW0 * hv[2][1] + BW1 * hv[3][1] + BW2 * hv[4][1] + BW3 * hv[5][1];
        d1.z = BW0 * hv[2][2] + BW1 * hv[3][2] + BW2 * hv[4][2] + BW3 * hv[5][2];
        d1.w = BW0 * hv[2][3] + BW1 * hv[3][3] + BW2 * hv[4][3] + BW3 * hv[5][3];

        *(f32x4*)&sD[2 * hp    ][4 * w4] = d0;
        *(f32x4*)&sD[2 * hp + 1][4 * w4] = d1;
    }

    __syncthreads();

    // ---- phase B: wave w writes output tensor t=w, 4 channel-block streams,
    //      each as a 16-row (16 KB) sequential burst ----
    const int wave = tid >> 6;
    const int lane = tid & 63;
    const int c  = bc % 3;
    const int b  = bc / 3;

    float* outT = out + (size_t)wave * TENSOR_STRIDE
                + (size_t)b * (12 * PLANE_OUT)
                + (size_t)c * PLANE_OUT
                + (size_t)(16 * s) * W_OUT
                + (size_t)(4 * lane);

    #pragma unroll
    for (int cb = 0; cb < 4; ++cb) {
        const float sc = s_scale[wave * 4 + cb];
        float* p = outT + (size_t)cb * (3 * PLANE_OUT);
        #pragma unroll
        for (int rr = 0; rr < 16; ++rr) {
            f32x4 v = *(const f32x4*)&sD[rr][4 * lane];
            f32x4 o;
            o.x = v.x * sc; o.y = v.y * sc; o.z = v.z * sc; o.w = v.w * sc;
            __builtin_nontemporal_store(o, (f32x4*)(p + (size_t)rr * W_OUT));
        }
    }
}

extern "C" void kernel_launch(void* const* d_in, const int* in_sizes, int n_in,
                              void* d_out, int out_size, void* d_ws, size_t ws_size,
                              hipStream_t stream) {
    const float* img = (const float*)d_in[0];
    const float* gl  = (const float*)d_in[1];
    const float* gh  = (const float*)d_in[2];
    const float* fl  = (const float*)d_in[3];
    const float* fh  = (const float*)d_in[4];
    float* out = (float*)d_out;

    // 48 planes x 16 slabs of 16 output rows = 768 blocks (3 per CU)
    const int threads = 256;
    const int blocks  = 48 * 16;
    qwt_fused_kernel<<<blocks, threads, 0, stream>>>(img, gl, gh, fl, fh, out);
}

// Round 10
// 245.761 us; speedup vs baseline: 1.0025x; 1.0025x over previous
//
#include <hip/hip_runtime.h>

// QWTForward: all 16 output blocks are (S_A*S_B)*D, D = bicubic downsample.
// R8 post-mortem: per-wave write burst restructure = null. Kernel stuck at
// ~115us (2.2 TB/s) while poison-fill hits 6.6 TB/s on the same buffer.
// R9 theory: GLOBAL concurrent write-stream count (~10k regions, all waves x
// 16 streams) exceeds open-DRAM-page capacity (~4k); fill has one compact
// moving window. Fix: two dispatches via d_ws.
//   A: compute D (12.6MB) once into workspace, XCD-pinned by plane (blk%8).
//   B: each block owns ONE (t,cb,plane,32-row slab): read 32KB D (L2/L3-hot),
//      write 32KB linearly -> ~2k compact global write windows, fill-like.

#define BW0 -0.09375f
#define BW1  0.59375f
#define BW2  0.59375f
#define BW3 -0.09375f

#define H_IN  512
#define W_IN  512
#define H_OUT 256
#define W_OUT 256
#define PLANE_OUT (H_OUT * W_OUT)          // 65536
#define TENSOR_STRIDE (16 * 12 * PLANE_OUT) // floats per out tensor

typedef __attribute__((ext_vector_type(4))) float f32x4;

// ---------------- Kernel A: D = bicubic-downsample(image) -> ws ----------------
__global__ __launch_bounds__(256) void qwt_downsample_kernel(
    const float* __restrict__ img, float* __restrict__ wsD)
{
    // blk = s*48 + bc  (48%8==0 -> blk%8 == bc%8: plane pinned to XCD bc%8)
    const int blk = blockIdx.x;
    const int bc  = blk % 48;
    const int s   = blk / 48;            // slab: out rows 16s..16s+15
    const int tid = threadIdx.x;
    const int w4  = tid & 63;            // out col group 4w4..4w4+3
    const int hpL = tid >> 6;            // 0..3

    const float* plane  = img + (size_t)bc * (H_IN * W_IN);
    float*       dplane = wsD + (size_t)bc * PLANE_OUT;

    const int cbase = w4 * 8;
    int clo = cbase - 1; if (clo < 0) clo = 0;
    int chi = cbase + 8; if (chi > W_IN - 1) chi = W_IN - 1;

    #pragma unroll
    for (int u = 0; u < 2; ++u) {
        const int hp = hpL + 4 * u;      // row-pair within slab, 0..7

        int r[6];
        #pragma unroll
        for (int i = 0; i < 6; ++i) {
            int rr = 32 * s + 4 * hp - 1 + i;
            r[i] = rr < 0 ? 0 : (rr > H_IN - 1 ? H_IN - 1 : rr);
        }

        float hv[6][4];
        #pragma unroll
        for (int i = 0; i < 6; ++i) {
            const float* rowp = plane + (size_t)r[i] * W_IN;
            const float4 a  = *(const float4*)(rowp + cbase);
            const float4 b4 = *(const float4*)(rowp + cbase + 4);
            const float v0 = rowp[clo];
            const float v9 = rowp[chi];
            const float v1 = a.x,  v2 = a.y,  v3 = a.z,  v4 = a.w;
            const float v5 = b4.x, v6 = b4.y, v7 = b4.z, v8 = b4.w;
            hv[i][0] = BW0 * v0 + BW1 * v1 + BW2 * v2 + BW3 * v3;
            hv[i][1] = BW0 * v2 + BW1 * v3 + BW2 * v4 + BW3 * v5;
            hv[i][2] = BW0 * v4 + BW1 * v5 + BW2 * v6 + BW3 * v7;
            hv[i][3] = BW0 * v6 + BW1 * v7 + BW2 * v8 + BW3 * v9;
        }

        f32x4 d0, d1;
        d0.x = BW0 * hv[0][0] + BW1 * hv[1][0] + BW2 * hv[2][0] + BW3 * hv[3][0];
        d0.y = BW0 * hv[0][1] + BW1 * hv[1][1] + BW2 * hv[2][1] + BW3 * hv[3][1];
        d0.z = BW0 * hv[0][2] + BW1 * hv[1][2] + BW2 * hv[2][2] + BW3 * hv[3][2];
        d0.w = BW0 * hv[0][3] + BW1 * hv[1][3] + BW2 * hv[2][3] + BW3 * hv[3][3];
        d1.x = BW0 * hv[2][0] + BW1 * hv[3][0] + BW2 * hv[4][0] + BW3 * hv[5][0];
        d1.y = BW0 * hv[2][1] + BW1 * hv[3][1] + BW2 * hv[4][1] + BW3 * hv[5][1];
        d1.z = BW0 * hv[2][2] + BW1 * hv[3][2] + BW2 * hv[4][2] + BW3 * hv[5][2];
        d1.w = BW0 * hv[2][3] + BW1 * hv[3][3] + BW2 * hv[4][3] + BW3 * hv[5][3];

        const int row = 16 * s + 2 * hp;
        *(f32x4*)(dplane + (size_t)row       * W_OUT + 4 * w4) = d0;
        *(f32x4*)(dplane + (size_t)(row + 1) * W_OUT + 4 * w4) = d1;
    }
}

// -------- Kernel B: out[t][b][cb*3+c] = scale[t,cb] * D, linear writes --------
__global__ __launch_bounds__(256) void qwt_scatter_kernel(
    const float* __restrict__ wsD,
    const float* __restrict__ gl, const float* __restrict__ gh,
    const float* __restrict__ fl, const float* __restrict__ fh,
    float* __restrict__ out)
{
    __shared__ float s_scale[16];
    const int tid = threadIdx.x;

    if (tid < 64) {
        float vgl = 0.f, vgh = 0.f, vfl = 0.f, vfh = 0.f;
        if (tid < 30) { vgl = gl[tid]; vgh = gh[tid]; vfl = fl[tid]; vfh = fh[tid]; }
        #pragma unroll
        for (int m = 32; m >= 1; m >>= 1) {
            vgl += __shfl_xor(vgl, m);
            vgh += __shfl_xor(vgh, m);
            vfl += __shfl_xor(vfl, m);
            vfh += __shfl_xor(vfh, m);
        }
        if (tid < 16) {
            const int t = tid >> 2, cb = tid & 3;
            const float A = (t < 2) ? ((cb & 1) ? vfl : vgl)
                                    : ((cb & 1) ? vfh : vgh);
            const float B = (t & 1) ? ((cb < 2) ? vgh : vfh)
                                    : ((cb < 2) ? vgl : vfl);
            s_scale[tid] = A * B;
        }
    }
    __syncthreads();

    // blk = (((bcg*4 + t)*4 + cb)*8 + slab)*8 + xcd ; bc = bcg*8 + xcd
    // -> blk%8 pins block to the XCD whose L2 holds plane bc's D slice.
    const int blk  = blockIdx.x;
    const int xcd  = blk & 7;
    const int j    = blk >> 3;           // 0..767
    const int slab = j & 7;              // 32-row slab, fastest
    const int cb   = (j >> 3) & 3;
    const int t    = (j >> 5) & 3;
    const int bcg  = j >> 7;             // 0..5
    const int bc   = bcg * 8 + xcd;      // 0..47
    const int b    = bc / 3;
    const int c    = bc % 3;

    const float sc = s_scale[t * 4 + cb];

    const float* dsrc = wsD + (size_t)bc * PLANE_OUT + (size_t)slab * 32 * W_OUT;
    float* dst = out + (size_t)t * TENSOR_STRIDE
               + (size_t)b  * (12 * PLANE_OUT)
               + (size_t)cb * (3 * PLANE_OUT)
               + (size_t)c  * PLANE_OUT
               + (size_t)slab * 32 * W_OUT;

    const int tf = tid * 4;              // float offset within a 4KB sweep
    #pragma unroll
    for (int sw = 0; sw < 8; ++sw) {     // 8 sweeps x 1024 floats = 32 rows
        const int off = sw * 1024 + tf;
        f32x4 v = *(const f32x4*)(dsrc + off);
        f32x4 o;
        o.x = v.x * sc; o.y = v.y * sc; o.z = v.z * sc; o.w = v.w * sc;
        __builtin_nontemporal_store(o, (f32x4*)(dst + off));
    }
}

// ---------------- Fallback (R7 fused kernel) if ws too small ----------------
__global__ __launch_bounds__(256) void qwt_fused_kernel(
    const float* __restrict__ img,
    const float* __restrict__ gl, const float* __restrict__ gh,
    const float* __restrict__ fl, const float* __restrict__ fh,
    float* __restrict__ out)
{
    __shared__ float s_scale[16];
    __shared__ __align__(16) float sD[16][W_OUT];

    const int tid = threadIdx.x;

    if (tid < 64) {
        float vgl = 0.f, vgh = 0.f, vfl = 0.f, vfh = 0.f;
        if (tid < 30) { vgl = gl[tid]; vgh = gh[tid]; vfl = fl[tid]; vfh = fh[tid]; }
        #pragma unroll
        for (int m = 32; m >= 1; m >>= 1) {
            vgl += __shfl_xor(vgl, m);
            vgh += __shfl_xor(vgh, m);
            vfl += __shfl_xor(vfl, m);
            vfh += __shfl_xor(vfh, m);
        }
        if (tid < 16) {
            const int t = tid >> 2, cb = tid & 3;
            const float A = (t < 2) ? ((cb & 1) ? vfl : vgl)
                                    : ((cb & 1) ? vfh : vgh);
            const float B = (t & 1) ? ((cb < 2) ? vgh : vfh)
                                    : ((cb < 2) ? vgl : vfl);
            s_scale[tid] = A * B;
        }
    }

    const int blk = blockIdx.x;
    const int s   = blk & 15;
    const int bc  = blk >> 4;

    const float* plane = img + (size_t)bc * (H_IN * W_IN);

    const int w4  = tid & 63;
    const int hpL = tid >> 6;

    const int cbase = w4 * 8;
    int clo = cbase - 1; if (clo < 0) clo = 0;
    int chi = cbase + 8; if (chi > W_IN - 1) chi = W_IN - 1;

    #pragma unroll
    for (int u = 0; u < 2; ++u) {
        const int hp = hpL + 4 * u;
        int r[6];
        #pragma unroll
        for (int i = 0; i < 6; ++i) {
            int rr = 32 * s + 4 * hp - 1 + i;
            r[i] = rr < 0 ? 0 : (rr > H_IN - 1 ? H_IN - 1 : rr);
        }
        float hv[6][4];
        #pragma unroll
        for (int i = 0; i < 6; ++i) {
            const float* rowp = plane + (size_t)r[i] * W_IN;
            const float4 a  = *(const float4*)(rowp + cbase);
            const float4 b4 = *(const float4*)(rowp + cbase + 4);
            const float v0 = rowp[clo];
            const float v9 = rowp[chi];
            const float v1 = a.x,  v2 = a.y,  v3 = a.z,  v4 = a.w;
            const float v5 = b4.x, v6 = b4.y, v7 = b4.z, v8 = b4.w;
            hv[i][0] = BW0 * v0 + BW1 * v1 + BW2 * v2 + BW3 * v3;
            hv[i][1] = BW0 * v2 + BW1 * v3 + BW2 * v4 + BW3 * v5;
            hv[i][2] = BW0 * v4 + BW1 * v5 + BW2 * v6 + BW3 * v7;
            hv[i][3] = BW0 * v6 + BW1 * v7 + BW2 * v8 + BW3 * v9;
        }
        f32x4 d0, d1;
        d0.x = BW0 * hv[0][0] + BW1 * hv[1][0] + BW2 * hv[2][0] + BW3 * hv[3][0];
        d0.y = BW0 * hv[0][1] + BW1 * hv[1][1] + BW2 * hv[2][1] + BW3 * hv[3][1];
        d0.z = BW0 * hv[0][2] + BW1 * hv[1][2] + BW2 * hv[2][2] + BW3 * hv[3][2];
        d0.w = BW0 * hv[0][3] + BW1 * hv[1][3] + BW2 * hv[2][3] + BW3 * hv[3][3];
        d1.x = BW0 * hv[2][0] + BW1 * hv[3][0] + BW2 * hv[4][0] + BW3 * hv[5][0];
        d1.y = BW0 * hv[2][1] + BW1 * hv[3][1] + BW2 * hv[4][1] + BW3 * hv[5][1];
        d1.z = BW0 * hv[2][2] + BW1 * hv[3][2] + BW2 * hv[4][2] + BW3 * hv[5][2];
        d1.w = BW0 * hv[2][3] + BW1 * hv[3][3] + BW2 * hv[4][3] + BW3 * hv[5][3];

        *(f32x4*)&sD[2 * hp    ][4 * w4] = d0;
        *(f32x4*)&sD[2 * hp + 1][4 * w4] = d1;
    }

    __syncthreads();

    const int wave = tid >> 6;
    const int lane = tid & 63;
    const int c  = bc % 3;
    const int b  = bc / 3;

    float* outT = out + (size_t)wave * TENSOR_STRIDE
                + (size_t)b * (12 * PLANE_OUT)
                + (size_t)c * PLANE_OUT
                + (size_t)(16 * s) * W_OUT
                + (size_t)(4 * lane);

    #pragma unroll
    for (int cb = 0; cb < 4; ++cb) {
        const float scv = s_scale[wave * 4 + cb];
        float* p = outT + (size_t)cb * (3 * PLANE_OUT);
        #pragma unroll
        for (int rr = 0; rr < 16; ++rr) {
            f32x4 v = *(const f32x4*)&sD[rr][4 * lane];
            f32x4 o;
            o.x = v.x * scv; o.y = v.y * scv; o.z = v.z * scv; o.w = v.w * scv;
            __builtin_nontemporal_store(o, (f32x4*)(p + (size_t)rr * W_OUT));
        }
    }
}

extern "C" void kernel_launch(void* const* d_in, const int* in_sizes, int n_in,
                              void* d_out, int out_size, void* d_ws, size_t ws_size,
                              hipStream_t stream) {
    const float* img = (const float*)d_in[0];
    const float* gl  = (const float*)d_in[1];
    const float* gh  = (const float*)d_in[2];
    const float* fl  = (const float*)d_in[3];
    const float* fh  = (const float*)d_in[4];
    float* out = (float*)d_out;

    const size_t needD = (size_t)48 * PLANE_OUT * sizeof(float); // 12.6 MB
    if (d_ws != nullptr && ws_size >= needD) {
        float* wsD = (float*)d_ws;
        qwt_downsample_kernel<<<768, 256, 0, stream>>>(img, wsD);
        qwt_scatter_kernel<<<6144, 256, 0, stream>>>(wsD, gl, gh, fl, fh, out);
    } else {
        // fallback: fused single kernel (R7 structure)
        qwt_fused_kernel<<<768, 256, 0, stream>>>(img, gl, gh, fl, fh, out);
    }
}